// Round 10
// baseline (1334.679 us; speedup 1.0000x reference)
//
#include <hip/hip_runtime.h>

#define NN 50000
#define NE 800000
#define EPB 2048                       // edges per P1 block
#define NB1 ((NE + EPB - 1) / EPB)     // 391
#define NB1P 512                       // padded column count (power of 2)
#define NBUK ((NN + 255) / 256)        // 196 coarse buckets (dst>>8)
#define GEMM_NB ((NN + 63) / 64)       // 782
#define NCH ((NN + 31) / 32)           // 1563 node-chunks of 32
#define PGRID 782                      // persistent grid: 4 blocks/CU co-resident

typedef short bf16x8 __attribute__((ext_vector_type(8)));
typedef float f32x4 __attribute__((ext_vector_type(4)));
typedef unsigned u32x4 __attribute__((ext_vector_type(4)));

// ------------------------------------------------ bf16 helpers (ushort = bf16)
__device__ inline void bf16x8_to_f32(const u32x4 v, float* f) {
    f[0] = __uint_as_float(v.x << 16);
    f[1] = __uint_as_float(v.x & 0xffff0000u);
    f[2] = __uint_as_float(v.y << 16);
    f[3] = __uint_as_float(v.y & 0xffff0000u);
    f[4] = __uint_as_float(v.z << 16);
    f[5] = __uint_as_float(v.z & 0xffff0000u);
    f[6] = __uint_as_float(v.w << 16);
    f[7] = __uint_as_float(v.w & 0xffff0000u);
}

__device__ inline unsigned f32_to_bf16(float x) {  // RTNE
    unsigned u = __float_as_uint(x);
    return (u + 0x7fffu + ((u >> 16) & 1u)) >> 16;
}

__device__ inline u32x4 f32x8_to_bf16(const float* f) {
    u32x4 v;
    v.x = f32_to_bf16(f[0]) | (f32_to_bf16(f[1]) << 16);
    v.y = f32_to_bf16(f[2]) | (f32_to_bf16(f[3]) << 16);
    v.z = f32_to_bf16(f[4]) | (f32_to_bf16(f[5]) << 16);
    v.w = f32_to_bf16(f[6]) | (f32_to_bf16(f[7]) << 16);
    return v;
}

// ================================================ kA: {P1-count, W12T, cvec, scalar}
__global__ __launch_bounds__(256) void kA_kernel(
    const int* __restrict__ dst, int* __restrict__ H,
    const float* __restrict__ W1, const float* __restrict__ W2,
    unsigned short* __restrict__ W12T, const float* __restrict__ b1,
    float* __restrict__ cvec, float* __restrict__ scalar_slot) {
    const int b = blockIdx.x;
    if (b < NB1) {
        __shared__ int lh[NBUK];
        for (int t = threadIdx.x; t < NBUK; t += 256) lh[t] = 0;
        __syncthreads();
        int i = b * EPB + threadIdx.x * 8;
        if (i < NE) {  // NE % 8 == 0, chunks 8-aligned
            int4 d0 = *(const int4*)(dst + i);
            int4 d1 = *(const int4*)(dst + i + 4);
            atomicAdd(&lh[d0.x >> 8], 1);
            atomicAdd(&lh[d0.y >> 8], 1);
            atomicAdd(&lh[d0.z >> 8], 1);
            atomicAdd(&lh[d0.w >> 8], 1);
            atomicAdd(&lh[d1.x >> 8], 1);
            atomicAdd(&lh[d1.y >> 8], 1);
            atomicAdd(&lh[d1.z >> 8], 1);
            atomicAdd(&lh[d1.w >> 8], 1);
        }
        __syncthreads();
        for (int t = threadIdx.x; t < NBUK; t += 256) H[t * NB1P + b] = lh[t];
    } else if (b < NB1 + 64) {
        int i = (b - NB1) * 256 + threadIdx.x;  // i = n*256 + k, n<64, k<256
        int n = i >> 8, k = i & 255;
        float s = 0.f;
        for (int j = 0; j < 128; ++j)
            s += W1[(size_t)k * 128 + j] * W2[(size_t)j * 64 + n];
        W12T[i] = (unsigned short)f32_to_bf16(s);
    } else {
        int d = threadIdx.x;
        if (d < 64) {
            float s = 0.f;
            for (int k = 0; k < 128; ++k) s += b1[k] * W2[(size_t)k * 64 + d];
            cvec[d] = s;
        }
        if (threadIdx.x == 64 && scalar_slot) *scalar_slot = 10.0f;
    }
}

// ================================================ kC1: exclusive scan of each H row
__global__ __launch_bounds__(256) void kC1_kernel(int* __restrict__ H,
                                                  int* __restrict__ colsum) {
    __shared__ int ws[4];
    int* row = H + (size_t)blockIdx.x * NB1P;
    const int t = threadIdx.x;
    int a0 = row[2 * t], a1 = row[2 * t + 1];
    int p = a0 + a1;
    const int lane = t & 63;
    const int wid = t >> 6;
    int incl = p;
    #pragma unroll
    for (int off = 1; off < 64; off <<= 1) {
        int q = __shfl_up(incl, off);
        if (lane >= off) incl += q;
    }
    if (lane == 63) ws[wid] = incl;
    __syncthreads();
    int woff = 0;
    #pragma unroll
    for (int w = 0; w < 4; ++w)
        if (w < wid) woff += ws[w];
    int ex = woff + incl - p;
    row[2 * t] = ex;
    row[2 * t + 1] = ex + a0;
    if (t == 0) colsum[blockIdx.x] = ws[0] + ws[1] + ws[2] + ws[3];
}

// ================================================ kC2: scan bucket totals -> base
__global__ __launch_bounds__(256) void kC2_kernel(const int* __restrict__ colsum,
                                                  int* __restrict__ base,
                                                  int* __restrict__ row_ptr) {
    __shared__ int ws[4];
    const int t = threadIdx.x;
    int v = (t < NBUK) ? colsum[t] : 0;
    const int lane = t & 63;
    const int wid = t >> 6;
    int incl = v;
    #pragma unroll
    for (int off = 1; off < 64; off <<= 1) {
        int q = __shfl_up(incl, off);
        if (lane >= off) incl += q;
    }
    if (lane == 63) ws[wid] = incl;
    __syncthreads();
    int woff = 0;
    #pragma unroll
    for (int w = 0; w < 4; ++w)
        if (w < wid) woff += ws[w];
    if (t < NBUK) base[t] = woff + incl - v;
    if (t == 0) {
        base[NBUK] = NE;
        row_ptr[NN] = NE;
    }
}

// ================================================ kD: {P1-scatter || MFMA GEMM}
__global__ __launch_bounds__(256) void kD_kernel(
    const int* __restrict__ src, const int* __restrict__ dst,
    const float* __restrict__ w, const int* __restrict__ H,
    const int* __restrict__ base, unsigned* __restrict__ er1,
    unsigned char* __restrict__ d8, const float* __restrict__ A,
    const unsigned short* __restrict__ BT, unsigned short* __restrict__ C) {
    __shared__ unsigned short As[64][40];
    __shared__ unsigned short Bs[64][40];
    __shared__ int lh[NBUK];
    __shared__ int lb[NBUK];
    const int b = blockIdx.x;

    if (b < NB1) {
        for (int t = threadIdx.x; t < NBUK; t += 256) {
            lh[t] = 0;
            lb[t] = base[t] + H[(size_t)t * NB1P + b];  // this block's range per bin
        }
        __syncthreads();
        int i = b * EPB + threadIdx.x * 8;
        if (i < NE) {
            int4 d0 = *(const int4*)(dst + i);
            int4 d1 = *(const int4*)(dst + i + 4);
            int4 s0 = *(const int4*)(src + i);
            int4 s1 = *(const int4*)(src + i + 4);
            float4 w0 = *(const float4*)(w + i);
            float4 w1 = *(const float4*)(w + i + 4);
            int dd[8] = {d0.x, d0.y, d0.z, d0.w, d1.x, d1.y, d1.z, d1.w};
            int ss[8] = {s0.x, s0.y, s0.z, s0.w, s1.x, s1.y, s1.z, s1.w};
            float ww[8] = {w0.x, w0.y, w0.z, w0.w, w1.x, w1.y, w1.z, w1.w};
            #pragma unroll
            for (int q = 0; q < 8; ++q) {
                int bin = dd[q] >> 8;
                int lr = atomicAdd(&lh[bin], 1);  // LDS return: fast
                int pos = lb[bin] + lr;
                er1[pos] = (f32_to_bf16(ww[q]) << 16) | (unsigned)ss[q];
                d8[pos] = (unsigned char)(dd[q] & 255);
            }
        }
        return;
    }

    constexpr int N = 64, K = 256;
    constexpr int NT = N / 16;
    constexpr int KS = K / 32;
    const int tid = threadIdx.x;
    const int wave = tid >> 6;
    const int lane = tid & 63;
    const int lm = lane & 15;
    const int lq = lane >> 4;
    const int row0 = (b - NB1) * 64;
    const int m0 = wave * 16;

    f32x4 acc[NT] = {};

    for (int ks = 0; ks < KS; ++ks) {
        const int k0 = ks * 32;
        {
            int m = tid >> 2, kc = (tid & 3) * 8;
            int gm = row0 + m;
            if (gm >= NN) gm = NN - 1;
            float4 v0 = *(const float4*)(A + (size_t)gm * K + k0 + kc);
            float4 v1 = *(const float4*)(A + (size_t)gm * K + k0 + kc + 4);
            float f[8] = {v0.x, v0.y, v0.z, v0.w, v1.x, v1.y, v1.z, v1.w};
            *(u32x4*)&As[m][kc] = f32x8_to_bf16(f);
        }
        #pragma unroll
        for (int c = tid; c < N * 4; c += 256) {
            int n = c >> 2, kc = (c & 3) * 8;
            *(uint4*)&Bs[n][kc] = *(const uint4*)(BT + (size_t)n * K + k0 + kc);
        }
        __syncthreads();
        bf16x8 a = *(const bf16x8*)&As[m0 + lm][lq * 8];
        #pragma unroll
        for (int t = 0; t < NT; ++t) {
            bf16x8 bb = *(const bf16x8*)&Bs[t * 16 + lm][lq * 8];
            acc[t] = __builtin_amdgcn_mfma_f32_16x16x32_bf16(a, bb, acc[t], 0, 0, 0);
        }
        __syncthreads();
    }
    #pragma unroll
    for (int r = 0; r < 4; ++r) {
        int gm = row0 + m0 + lq * 4 + r;
        if (gm < NN) {
            #pragma unroll
            for (int t = 0; t < NT; ++t)
                C[(size_t)gm * N + t * 16 + lm] =
                    (unsigned short)f32_to_bf16(acc[t][r]);
        }
    }
}

// ================================================ kE: per-bucket final CSR build
__global__ __launch_bounds__(256) void kE_kernel(
    const int* __restrict__ base, const unsigned char* __restrict__ d8,
    const unsigned* __restrict__ er1, int* __restrict__ row_ptr,
    unsigned* __restrict__ er) {
    __shared__ int cnt[256];
    __shared__ int cur[256];
    __shared__ int ws[4];
    const int k = blockIdx.x;
    const int t = threadIdx.x;
    const int s = base[k];
    const int e_end = base[k + 1];

    cnt[t] = 0;
    __syncthreads();
    for (int e = s + t; e < e_end; e += 256) atomicAdd(&cnt[d8[e]], 1);
    __syncthreads();

    int v = cnt[t];
    const int lane = t & 63;
    const int wid = t >> 6;
    int incl = v;
    #pragma unroll
    for (int off = 1; off < 64; off <<= 1) {
        int q = __shfl_up(incl, off);
        if (lane >= off) incl += q;
    }
    if (lane == 63) ws[wid] = incl;
    __syncthreads();
    int woff = 0;
    #pragma unroll
    for (int w = 0; w < 4; ++w)
        if (w < wid) woff += ws[w];
    int ex = woff + incl - v;

    int node = k * 256 + t;
    if (node < NN) row_ptr[node] = s + ex;
    cur[t] = s + ex;
    __syncthreads();

    for (int e = s + t; e < e_end; e += 256) {
        int p = atomicAdd(&cur[d8[e]], 1);
        er[p] = er1[e];
    }
}

// ================================================ persistent APPNP: 12 props, 1 launch
// Software grid barrier (monotonic counter, device-scope atomics + threadfence
// for cross-XCD visibility). Regular launch -> graph-capturable.
// All PGRID blocks are co-resident: __launch_bounds__(256,4) => 4 blocks/CU,
// capacity 1024 >= 782, kernel runs alone on the stream.
__device__ inline void grid_barrier(int* bar, int target) {
    __syncthreads();
    if (threadIdx.x == 0) {
        __threadfence();                    // release: flush this XCD's writes
        atomicAdd(bar, 1);
        while (atomicAdd(bar, 0) < target)  // device-scope coherent poll
            __builtin_amdgcn_s_sleep(2);
        __threadfence();                    // acquire: invalidate stale caches
    }
    __syncthreads();
}

__global__ __launch_bounds__(256, 4) void appnp_persist_kernel(
    const int* __restrict__ row_ptr, const unsigned* __restrict__ er,
    const unsigned short* __restrict__ z_bf, unsigned short* __restrict__ p1_bf,
    unsigned short* __restrict__ h_bf, unsigned short* __restrict__ xb0,
    unsigned short* __restrict__ xb1, const float* __restrict__ cvec,
    const float* __restrict__ b2, float* __restrict__ degw,
    float* __restrict__ outf, int* __restrict__ bar) {
    constexpr int D = 64;
    const int local = threadIdx.x >> 3;     // node within chunk (32/chunk)
    const int lane = threadIdx.x & 7;       // 8 threads/node, 16B each
    const int wbase = threadIdx.x & 56;     // group base lane within wave

    for (int step = 0; step < 12; ++step) {
        const unsigned short* xin;
        unsigned short* outb = nullptr;
        float* outfp = nullptr;
        int mode;
        bool dg = false;
        if (step == 0) {
            xin = z_bf; outb = p1_bf; mode = 0; dg = true;
        } else if (step == 1) {
            xin = p1_bf; outb = h_bf; mode = 2;
        } else if (step == 11) {
            xin = xb0; outfp = outf; mode = 1;   // k=8 wrote xb0
        } else {
            int k = step - 2;  // 0..8
            xin = (k == 0) ? h_bf : ((k & 1) ? xb0 : xb1);
            outb = (k & 1) ? xb1 : xb0;
            mode = 1;
        }

        for (int c = blockIdx.x; c < NCH; c += gridDim.x) {
            const int n = c * 32 + local;
            if (n >= NN) continue;
            int e = row_ptr[n];
            const int end = row_ptr[n + 1];

            float acc[8] = {};
            float sw = 0.f;
            float f[8];

            for (; e + 7 < end; e += 8) {
                unsigned rq = er[e + lane];
                unsigned rr[8];
                #pragma unroll
                for (int q = 0; q < 8; ++q) rr[q] = __shfl(rq, wbase + q, 64);
                u32x4 uu[8];
                #pragma unroll
                for (int q = 0; q < 8; ++q)
                    uu[q] = *(const u32x4*)(xin + (size_t)(rr[q] & 0xffffu) * D +
                                            lane * 8);
                #pragma unroll
                for (int q = 0; q < 8; ++q) {
                    float wq = __uint_as_float(rr[q] & 0xffff0000u);
                    if (dg) sw += wq;
                    bf16x8_to_f32(uu[q], f);
                    #pragma unroll
                    for (int j = 0; j < 8; ++j) acc[j] += wq * f[j];
                }
            }
            for (; e + 3 < end; e += 4) {
                unsigned rr[4];
                #pragma unroll
                for (int q = 0; q < 4; ++q) rr[q] = er[e + q];
                u32x4 uu[4];
                #pragma unroll
                for (int q = 0; q < 4; ++q)
                    uu[q] = *(const u32x4*)(xin + (size_t)(rr[q] & 0xffffu) * D +
                                            lane * 8);
                #pragma unroll
                for (int q = 0; q < 4; ++q) {
                    float wq = __uint_as_float(rr[q] & 0xffff0000u);
                    if (dg) sw += wq;
                    bf16x8_to_f32(uu[q], f);
                    #pragma unroll
                    for (int j = 0; j < 8; ++j) acc[j] += wq * f[j];
                }
            }
            for (; e < end; ++e) {
                unsigned r0 = er[e];
                u32x4 u0 =
                    *(const u32x4*)(xin + (size_t)(r0 & 0xffffu) * D + lane * 8);
                float w0 = __uint_as_float(r0 & 0xffff0000u);
                if (dg) sw += w0;
                bf16x8_to_f32(u0, f);
                #pragma unroll
                for (int j = 0; j < 8; ++j) acc[j] += w0 * f[j];
            }

            if (dg && lane == 0) degw[n] = sw;

            float r[8];
            if (mode == 0) {
                #pragma unroll
                for (int j = 0; j < 8; ++j) r[j] = acc[j];
            } else if (mode == 2) {
                float dw = degw[n];
                #pragma unroll
                for (int j = 0; j < 8; ++j)
                    r[j] = acc[j] + dw * cvec[lane * 8 + j] + b2[lane * 8 + j];
            } else {
                u32x4 uh = *(const u32x4*)(h_bf + (size_t)n * D + lane * 8);
                float fh[8];
                bf16x8_to_f32(uh, fh);
                #pragma unroll
                for (int j = 0; j < 8; ++j) r[j] = 0.9f * acc[j] + 0.1f * fh[j];
            }

            if (outfp) {
                float* o = outfp + (size_t)n * D + lane * 8;
                *(float4*)(o + 0) = make_float4(r[0], r[1], r[2], r[3]);
                *(float4*)(o + 4) = make_float4(r[4], r[5], r[6], r[7]);
            } else {
                *(u32x4*)(outb + (size_t)n * D + lane * 8) = f32x8_to_bf16(r);
            }
        }
        if (step < 11) grid_barrier(bar, PGRID * (step + 1));
    }
}

// ------------------------------------------------ launch
extern "C" void kernel_launch(void* const* d_in, const int* in_sizes, int n_in,
                              void* d_out, int out_size, void* d_ws, size_t ws_size,
                              hipStream_t stream) {
    const float* features = (const float*)d_in[0];
    const int* edge_index = (const int*)d_in[1];
    const float* edge_w = (const float*)d_in[2];
    const float* W1 = (const float*)d_in[3];
    const float* b1 = (const float*)d_in[4];
    const float* W2 = (const float*)d_in[5];
    const float* b2 = (const float*)d_in[6];
    const int* src = edge_index;        // edge_index[0]
    const int* dst = edge_index + NE;   // edge_index[1]

    char* ws = (char*)d_ws;
    auto carve = [&](size_t bytes) {
        char* p = ws;
        ws += (bytes + 255) & ~(size_t)255;
        return p;
    };
    int* H = (int*)carve((size_t)NBUK * NB1P * 4);    // per-(bin,block) matrix
    int* colsum = (int*)carve((size_t)NBUK * 4);
    int* base = (int*)carve((size_t)(NBUK + 1) * 4);
    int* row_ptr = (int*)carve((size_t)(NN + 1) * 4);
    unsigned* er1 = (unsigned*)carve((size_t)NE * 4); // bucket-grouped records
    unsigned char* d8 = (unsigned char*)carve((size_t)NE);
    unsigned* erec = (unsigned*)carve((size_t)NE * 4);
    float* degw = (float*)carve((size_t)NN * 4);
    float* cvec = (float*)carve((size_t)64 * 4);
    unsigned short* W12T = (unsigned short*)carve((size_t)64 * 256 * 2);
    unsigned short* z_bf = (unsigned short*)carve((size_t)NN * 64 * 2);
    unsigned short* p1_bf = (unsigned short*)carve((size_t)NN * 64 * 2);
    unsigned short* h_bf = (unsigned short*)carve((size_t)NN * 64 * 2);
    unsigned short* xb0 = (unsigned short*)carve((size_t)NN * 64 * 2);
    unsigned short* xb1 = (unsigned short*)carve((size_t)NN * 64 * 2);
    int* bar = (int*)carve((size_t)256);              // barrier counter

    float* scalar_slot =
        (out_size > NN * 64) ? ((float*)d_out + (size_t)NN * 64) : nullptr;
    float* outf = (float*)d_out;

    // ---- kA: {P1-count, W12T, cvec, scalar} ----
    hipMemsetAsync(H, 0, (size_t)NBUK * NB1P * 4, stream);
    hipMemsetAsync(bar, 0, 256, stream);
    kA_kernel<<<NB1 + 64 + 1, 256, 0, stream>>>(dst, H, W1, W2, W12T, b1, cvec,
                                                scalar_slot);

    // ---- kC1/kC2: matrix scans (atomic-free placement ranges) ----
    kC1_kernel<<<NBUK, 256, 0, stream>>>(H, colsum);
    kC2_kernel<<<1, 256, 0, stream>>>(colsum, base, row_ptr);

    // ---- kD: {P1-scatter || GEMM z = F @ W12} ----
    kD_kernel<<<NB1 + GEMM_NB, 256, 0, stream>>>(src, dst, edge_w, H, base, er1,
                                                 d8, features, W12T, z_bf);

    // ---- kE: per-bucket final CSR (row_ptr + er) ----
    kE_kernel<<<NBUK, 256, 0, stream>>>(base, d8, er1, row_ptr, erec);

    // ---- all 12 propagation steps in ONE persistent launch ----
    appnp_persist_kernel<<<PGRID, 256, 0, stream>>>(row_ptr, erec, z_bf, p1_bf,
                                                    h_bf, xb0, xb1, cvec, b2,
                                                    degw, outf, bar);
}

// Round 11
// 323.261 us; speedup vs baseline: 4.1288x; 4.1288x over previous
//
#include <hip/hip_runtime.h>

#define NN 50000
#define NE 800000
#define EPB 2048                       // edges per P1 block
#define NB1 ((NE + EPB - 1) / EPB)     // 391
#define NB1P 512                       // padded column count (power of 2)
#define NBUK ((NN + 255) / 256)        // 196 coarse buckets (dst>>8)
#define GEMM_NB ((NN + 63) / 64)       // 782

typedef short bf16x8 __attribute__((ext_vector_type(8)));
typedef float f32x4 __attribute__((ext_vector_type(4)));
typedef unsigned u32x4 __attribute__((ext_vector_type(4)));

// ------------------------------------------------ bf16 helpers (ushort = bf16)
__device__ inline void bf16x8_to_f32(const u32x4 v, float* f) {
    f[0] = __uint_as_float(v.x << 16);
    f[1] = __uint_as_float(v.x & 0xffff0000u);
    f[2] = __uint_as_float(v.y << 16);
    f[3] = __uint_as_float(v.y & 0xffff0000u);
    f[4] = __uint_as_float(v.z << 16);
    f[5] = __uint_as_float(v.z & 0xffff0000u);
    f[6] = __uint_as_float(v.w << 16);
    f[7] = __uint_as_float(v.w & 0xffff0000u);
}

__device__ inline unsigned f32_to_bf16(float x) {  // RTNE
    unsigned u = __float_as_uint(x);
    return (u + 0x7fffu + ((u >> 16) & 1u)) >> 16;
}

__device__ inline u32x4 f32x8_to_bf16(const float* f) {
    u32x4 v;
    v.x = f32_to_bf16(f[0]) | (f32_to_bf16(f[1]) << 16);
    v.y = f32_to_bf16(f[2]) | (f32_to_bf16(f[3]) << 16);
    v.z = f32_to_bf16(f[4]) | (f32_to_bf16(f[5]) << 16);
    v.w = f32_to_bf16(f[6]) | (f32_to_bf16(f[7]) << 16);
    return v;
}

// ================================================ kA: {P1-count, W12T, cvec, scalar}
__global__ __launch_bounds__(256) void kA_kernel(
    const int* __restrict__ dst, int* __restrict__ H,
    const float* __restrict__ W1, const float* __restrict__ W2,
    unsigned short* __restrict__ W12T, const float* __restrict__ b1,
    float* __restrict__ cvec, float* __restrict__ scalar_slot) {
    const int b = blockIdx.x;
    if (b < NB1) {
        __shared__ int lh[NBUK];
        for (int t = threadIdx.x; t < NBUK; t += 256) lh[t] = 0;
        __syncthreads();
        int i = b * EPB + threadIdx.x * 8;
        if (i < NE) {  // NE % 8 == 0, chunks 8-aligned
            int4 d0 = *(const int4*)(dst + i);
            int4 d1 = *(const int4*)(dst + i + 4);
            atomicAdd(&lh[d0.x >> 8], 1);
            atomicAdd(&lh[d0.y >> 8], 1);
            atomicAdd(&lh[d0.z >> 8], 1);
            atomicAdd(&lh[d0.w >> 8], 1);
            atomicAdd(&lh[d1.x >> 8], 1);
            atomicAdd(&lh[d1.y >> 8], 1);
            atomicAdd(&lh[d1.z >> 8], 1);
            atomicAdd(&lh[d1.w >> 8], 1);
        }
        __syncthreads();
        for (int t = threadIdx.x; t < NBUK; t += 256) H[t * NB1P + b] = lh[t];
    } else if (b < NB1 + 64) {
        int i = (b - NB1) * 256 + threadIdx.x;  // i = n*256 + k, n<64, k<256
        int n = i >> 8, k = i & 255;
        float s = 0.f;
        for (int j = 0; j < 128; ++j)
            s += W1[(size_t)k * 128 + j] * W2[(size_t)j * 64 + n];
        W12T[i] = (unsigned short)f32_to_bf16(s);
    } else {
        int d = threadIdx.x;
        if (d < 64) {
            float s = 0.f;
            for (int k = 0; k < 128; ++k) s += b1[k] * W2[(size_t)k * 64 + d];
            cvec[d] = s;
        }
        if (threadIdx.x == 64 && scalar_slot) *scalar_slot = 10.0f;
    }
}

// ================================================ kC1: exclusive scan of each H row
// Reads guarded at col >= NB1 (no memset needed for the padding columns).
__global__ __launch_bounds__(256) void kC1_kernel(int* __restrict__ H,
                                                  int* __restrict__ colsum) {
    __shared__ int ws[4];
    int* row = H + (size_t)blockIdx.x * NB1P;
    const int t = threadIdx.x;
    int a0 = (2 * t < NB1) ? row[2 * t] : 0;
    int a1 = (2 * t + 1 < NB1) ? row[2 * t + 1] : 0;
    int p = a0 + a1;
    const int lane = t & 63;
    const int wid = t >> 6;
    int incl = p;
    #pragma unroll
    for (int off = 1; off < 64; off <<= 1) {
        int q = __shfl_up(incl, off);
        if (lane >= off) incl += q;
    }
    if (lane == 63) ws[wid] = incl;
    __syncthreads();
    int woff = 0;
    #pragma unroll
    for (int w = 0; w < 4; ++w)
        if (w < wid) woff += ws[w];
    int ex = woff + incl - p;
    if (2 * t < NB1) row[2 * t] = ex;
    if (2 * t + 1 < NB1) row[2 * t + 1] = ex + a0;
    if (t == 0) colsum[blockIdx.x] = ws[0] + ws[1] + ws[2] + ws[3];
}

// ================================================ kD: {P1-scatter || MFMA GEMM}
// Scatter blocks recompute bucket base via in-LDS scan of colsum (kC2 removed).
__global__ __launch_bounds__(256) void kD_kernel(
    const int* __restrict__ src, const int* __restrict__ dst,
    const float* __restrict__ w, const int* __restrict__ H,
    const int* __restrict__ colsum, unsigned* __restrict__ er1,
    unsigned char* __restrict__ d8, const float* __restrict__ A,
    const unsigned short* __restrict__ BT, unsigned short* __restrict__ C) {
    __shared__ unsigned short As[64][40];
    __shared__ unsigned short Bs[64][40];
    __shared__ int lh[NBUK];
    __shared__ int lb[NBUK];
    __shared__ int ws[4];
    const int b = blockIdx.x;

    if (b < NB1) {
        const int t = threadIdx.x;
        {   // exclusive scan of colsum -> bucket base, + this block's H offset
            int v = (t < NBUK) ? colsum[t] : 0;
            const int lane = t & 63;
            const int wid = t >> 6;
            int incl = v;
            #pragma unroll
            for (int off = 1; off < 64; off <<= 1) {
                int q = __shfl_up(incl, off);
                if (lane >= off) incl += q;
            }
            if (lane == 63) ws[wid] = incl;
            __syncthreads();
            int woff = 0;
            #pragma unroll
            for (int w4 = 0; w4 < 4; ++w4)
                if (w4 < wid) woff += ws[w4];
            int ex = woff + incl - v;
            if (t < NBUK) {
                lh[t] = 0;
                lb[t] = ex + H[(size_t)t * NB1P + b];
            }
        }
        __syncthreads();
        int i = b * EPB + threadIdx.x * 8;
        if (i < NE) {
            int4 d0 = *(const int4*)(dst + i);
            int4 d1 = *(const int4*)(dst + i + 4);
            int4 s0 = *(const int4*)(src + i);
            int4 s1 = *(const int4*)(src + i + 4);
            float4 w0 = *(const float4*)(w + i);
            float4 w1 = *(const float4*)(w + i + 4);
            int dd[8] = {d0.x, d0.y, d0.z, d0.w, d1.x, d1.y, d1.z, d1.w};
            int ss[8] = {s0.x, s0.y, s0.z, s0.w, s1.x, s1.y, s1.z, s1.w};
            float ww[8] = {w0.x, w0.y, w0.z, w0.w, w1.x, w1.y, w1.z, w1.w};
            #pragma unroll
            for (int q = 0; q < 8; ++q) {
                int bin = dd[q] >> 8;
                int lr = atomicAdd(&lh[bin], 1);  // LDS return: fast
                int pos = lb[bin] + lr;
                er1[pos] = (f32_to_bf16(ww[q]) << 16) | (unsigned)ss[q];
                d8[pos] = (unsigned char)(dd[q] & 255);
            }
        }
        return;
    }

    constexpr int N = 64, K = 256;
    constexpr int NT = N / 16;
    constexpr int KS = K / 32;
    const int tid = threadIdx.x;
    const int wave = tid >> 6;
    const int lane = tid & 63;
    const int lm = lane & 15;
    const int lq = lane >> 4;
    const int row0 = (b - NB1) * 64;
    const int m0 = wave * 16;

    f32x4 acc[NT] = {};

    for (int ks = 0; ks < KS; ++ks) {
        const int k0 = ks * 32;
        {
            int m = tid >> 2, kc = (tid & 3) * 8;
            int gm = row0 + m;
            if (gm >= NN) gm = NN - 1;
            float4 v0 = *(const float4*)(A + (size_t)gm * K + k0 + kc);
            float4 v1 = *(const float4*)(A + (size_t)gm * K + k0 + kc + 4);
            float f[8] = {v0.x, v0.y, v0.z, v0.w, v1.x, v1.y, v1.z, v1.w};
            *(u32x4*)&As[m][kc] = f32x8_to_bf16(f);
        }
        #pragma unroll
        for (int c = tid; c < N * 4; c += 256) {
            int n = c >> 2, kc = (c & 3) * 8;
            *(uint4*)&Bs[n][kc] = *(const uint4*)(BT + (size_t)n * K + k0 + kc);
        }
        __syncthreads();
        bf16x8 a = *(const bf16x8*)&As[m0 + lm][lq * 8];
        #pragma unroll
        for (int t = 0; t < NT; ++t) {
            bf16x8 bb = *(const bf16x8*)&Bs[t * 16 + lm][lq * 8];
            acc[t] = __builtin_amdgcn_mfma_f32_16x16x32_bf16(a, bb, acc[t], 0, 0, 0);
        }
        __syncthreads();
    }
    #pragma unroll
    for (int r = 0; r < 4; ++r) {
        int gm = row0 + m0 + lq * 4 + r;
        if (gm < NN) {
            #pragma unroll
            for (int t = 0; t < NT; ++t)
                C[(size_t)gm * N + t * 16 + lm] =
                    (unsigned short)f32_to_bf16(acc[t][r]);
        }
    }
}

// ================================================ kE: per-bucket final CSR build
// Recomputes bucket base via in-LDS scan of colsum (kC2 removed); writes row_ptr.
__global__ __launch_bounds__(256) void kE_kernel(
    const int* __restrict__ colsum, const unsigned char* __restrict__ d8,
    const unsigned* __restrict__ er1, int* __restrict__ row_ptr,
    unsigned* __restrict__ er) {
    __shared__ int bs[257];
    __shared__ int cnt[256];
    __shared__ int cur[256];
    __shared__ int ws[4];
    const int k = blockIdx.x;
    const int t = threadIdx.x;

    {   // exclusive scan of colsum -> bucket bases
        int v = (t < NBUK) ? colsum[t] : 0;
        const int lane = t & 63;
        const int wid = t >> 6;
        int incl = v;
        #pragma unroll
        for (int off = 1; off < 64; off <<= 1) {
            int q = __shfl_up(incl, off);
            if (lane >= off) incl += q;
        }
        if (lane == 63) ws[wid] = incl;
        __syncthreads();
        int woff = 0;
        #pragma unroll
        for (int w = 0; w < 4; ++w)
            if (w < wid) woff += ws[w];
        bs[t] = woff + incl - v;
        if (t == 255) bs[256] = woff + incl;
        cnt[t] = 0;
    }
    __syncthreads();

    const int s = bs[k];
    const int e_end = bs[k + 1];

    for (int e = s + t; e < e_end; e += 256) atomicAdd(&cnt[d8[e]], 1);
    __syncthreads();

    int v = cnt[t];
    const int lane = t & 63;
    const int wid = t >> 6;
    int incl = v;
    #pragma unroll
    for (int off = 1; off < 64; off <<= 1) {
        int q = __shfl_up(incl, off);
        if (lane >= off) incl += q;
    }
    if (lane == 63) ws[wid] = incl;
    __syncthreads();
    int woff = 0;
    #pragma unroll
    for (int w = 0; w < 4; ++w)
        if (w < wid) woff += ws[w];
    int ex = woff + incl - v;

    int node = k * 256 + t;
    if (node < NN) row_ptr[node] = s + ex;
    if (k == NBUK - 1 && t == 0) row_ptr[NN] = NE;
    cur[t] = s + ex;
    __syncthreads();

    for (int e = s + t; e < e_end; e += 256) {
        int p = atomicAdd(&cur[d8[e]], 1);
        er[p] = er1[e];
    }
}

// ------------------------------------------------ propagation D=64 (bf16, 4B rec)
// rec = bf16(w)<<16 | src (src < 65536 since NN=50000).  (known-best form)
// MODE 0: out = acc                         (conv1-fused; DEGW: also sum w)
// MODE 2: out = acc + degw[n]*c[d] + b2[d]  (conv2 epilogue)
// MODE 1: out = 0.9*acc + 0.1*h[n][d]       (APPNP step)
template <int MODE, bool OUT_BF16, bool DEGW>
__global__ __launch_bounds__(256, 4) void prop_kernel(
    const int* __restrict__ row_ptr, const unsigned* __restrict__ er,
    const unsigned short* __restrict__ x, const float* __restrict__ cvec,
    const float* __restrict__ b2, float* __restrict__ degw,
    const unsigned short* __restrict__ hbf, void* __restrict__ outv) {
    constexpr int D = 64;
    const int local = threadIdx.x >> 3;     // node within block (32/block)
    const int lane = threadIdx.x & 7;       // 8 threads/node, 16B each
    const int wbase = threadIdx.x & 56;     // group base lane within wave
    const int n = blockIdx.x * 32 + local;
    if (n >= NN) return;

    int e = row_ptr[n];
    const int end = row_ptr[n + 1];

    float acc[8] = {};
    float sw = 0.f;
    float f[8];

    for (; e + 7 < end; e += 8) {
        unsigned rq = er[e + lane];
        unsigned rr[8];
        #pragma unroll
        for (int q = 0; q < 8; ++q) rr[q] = __shfl(rq, wbase + q, 64);
        u32x4 uu[8];
        #pragma unroll
        for (int q = 0; q < 8; ++q)
            uu[q] = *(const u32x4*)(x + (size_t)(rr[q] & 0xffffu) * D + lane * 8);
        #pragma unroll
        for (int q = 0; q < 8; ++q) {
            float wq = __uint_as_float(rr[q] & 0xffff0000u);
            if (DEGW) sw += wq;
            bf16x8_to_f32(uu[q], f);
            #pragma unroll
            for (int j = 0; j < 8; ++j) acc[j] += wq * f[j];
        }
    }
    for (; e + 3 < end; e += 4) {
        unsigned rr[4];
        #pragma unroll
        for (int q = 0; q < 4; ++q) rr[q] = er[e + q];
        u32x4 uu[4];
        #pragma unroll
        for (int q = 0; q < 4; ++q)
            uu[q] = *(const u32x4*)(x + (size_t)(rr[q] & 0xffffu) * D + lane * 8);
        #pragma unroll
        for (int q = 0; q < 4; ++q) {
            float wq = __uint_as_float(rr[q] & 0xffff0000u);
            if (DEGW) sw += wq;
            bf16x8_to_f32(uu[q], f);
            #pragma unroll
            for (int j = 0; j < 8; ++j) acc[j] += wq * f[j];
        }
    }
    for (; e < end; ++e) {
        unsigned r0 = er[e];
        u32x4 u0 = *(const u32x4*)(x + (size_t)(r0 & 0xffffu) * D + lane * 8);
        float w0 = __uint_as_float(r0 & 0xffff0000u);
        if (DEGW) sw += w0;
        bf16x8_to_f32(u0, f);
        #pragma unroll
        for (int j = 0; j < 8; ++j) acc[j] += w0 * f[j];
    }

    if (DEGW) {
        if (lane == 0) degw[n] = sw;
    }

    float r[8];
    if (MODE == 0) {
        #pragma unroll
        for (int j = 0; j < 8; ++j) r[j] = acc[j];
    } else if (MODE == 2) {
        float dw = degw[n];
        #pragma unroll
        for (int j = 0; j < 8; ++j)
            r[j] = acc[j] + dw * cvec[lane * 8 + j] + b2[lane * 8 + j];
    } else {
        u32x4 uh = *(const u32x4*)(hbf + (size_t)n * D + lane * 8);
        float fh[8];
        bf16x8_to_f32(uh, fh);
        #pragma unroll
        for (int j = 0; j < 8; ++j) r[j] = 0.9f * acc[j] + 0.1f * fh[j];
    }

    if (OUT_BF16) {
        *(u32x4*)((unsigned short*)outv + (size_t)n * D + lane * 8) =
            f32x8_to_bf16(r);
    } else {
        float* o = (float*)outv + (size_t)n * D + lane * 8;
        *(float4*)(o + 0) = make_float4(r[0], r[1], r[2], r[3]);
        *(float4*)(o + 4) = make_float4(r[4], r[5], r[6], r[7]);
    }
}

// ------------------------------------------------ launch
extern "C" void kernel_launch(void* const* d_in, const int* in_sizes, int n_in,
                              void* d_out, int out_size, void* d_ws, size_t ws_size,
                              hipStream_t stream) {
    const float* features = (const float*)d_in[0];
    const int* edge_index = (const int*)d_in[1];
    const float* edge_w = (const float*)d_in[2];
    const float* W1 = (const float*)d_in[3];
    const float* b1 = (const float*)d_in[4];
    const float* W2 = (const float*)d_in[5];
    const float* b2 = (const float*)d_in[6];
    const int* src = edge_index;        // edge_index[0]
    const int* dst = edge_index + NE;   // edge_index[1]

    char* ws = (char*)d_ws;
    auto carve = [&](size_t bytes) {
        char* p = ws;
        ws += (bytes + 255) & ~(size_t)255;
        return p;
    };
    int* H = (int*)carve((size_t)NBUK * NB1P * 4);    // per-(bin,block) matrix
    int* colsum = (int*)carve((size_t)NBUK * 4);
    int* row_ptr = (int*)carve((size_t)(NN + 1) * 4);
    unsigned* er1 = (unsigned*)carve((size_t)NE * 4); // bucket-grouped records
    unsigned char* d8 = (unsigned char*)carve((size_t)NE);
    unsigned* erec = (unsigned*)carve((size_t)NE * 4);
    float* degw = (float*)carve((size_t)NN * 4);
    float* cvec = (float*)carve((size_t)64 * 4);
    unsigned short* W12T = (unsigned short*)carve((size_t)64 * 256 * 2);
    unsigned short* z_bf = (unsigned short*)carve((size_t)NN * 64 * 2);
    unsigned short* p1_bf = (unsigned short*)carve((size_t)NN * 64 * 2);
    unsigned short* h_bf = (unsigned short*)carve((size_t)NN * 64 * 2);
    unsigned short* xb0 = (unsigned short*)carve((size_t)NN * 64 * 2);
    unsigned short* xb1 = (unsigned short*)carve((size_t)NN * 64 * 2);

    const int PB = (NN + 31) / 32;   // prop blocks (32 nodes each)

    float* scalar_slot =
        (out_size > NN * 64) ? ((float*)d_out + (size_t)NN * 64) : nullptr;

    // ---- kA: {P1-count, W12T, cvec, scalar} ----
    kA_kernel<<<NB1 + 64 + 1, 256, 0, stream>>>(dst, H, W1, W2, W12T, b1, cvec,
                                                scalar_slot);

    // ---- kC1: per-bucket exclusive scan of H rows ----
    kC1_kernel<<<NBUK, 256, 0, stream>>>(H, colsum);

    // ---- kD: {P1-scatter || GEMM z = F @ W12} ----
    kD_kernel<<<NB1 + GEMM_NB, 256, 0, stream>>>(src, dst, edge_w, H, colsum, er1,
                                                 d8, features, W12T, z_bf);

    // ---- kE: per-bucket final CSR (row_ptr + er) ----
    kE_kernel<<<NBUK, 256, 0, stream>>>(colsum, d8, er1, row_ptr, erec);

    // ---- p1 = prop(z) [+degw];  h = prop(p1) + degw*c + b2 ----
    prop_kernel<0, true, true><<<PB, 256, 0, stream>>>(row_ptr, erec, z_bf, nullptr,
                                                       nullptr, degw, nullptr,
                                                       p1_bf);
    prop_kernel<2, true, false><<<PB, 256, 0, stream>>>(row_ptr, erec, p1_bf, cvec,
                                                        b2, degw, nullptr, h_bf);

    // ---- APPNP: 10 steps of x = 0.9*prop(x) + 0.1*h ----
    const unsigned short* x_cur = h_bf;
    for (int k = 0; k < 9; ++k) {
        unsigned short* out = (k & 1) ? xb1 : xb0;
        prop_kernel<1, true, false><<<PB, 256, 0, stream>>>(row_ptr, erec, x_cur,
                                                            nullptr, nullptr,
                                                            nullptr, h_bf, out);
        x_cur = out;
    }
    prop_kernel<1, false, false><<<PB, 256, 0, stream>>>(row_ptr, erec, x_cur,
                                                         nullptr, nullptr, nullptr,
                                                         h_bf, (float*)d_out);
}